// Round 15
// baseline (61.395 us; speedup 1.0000x reference)
//
#include <hip/hip_runtime.h>
#include <math.h>

// Problem constants (from reference)
#define M_SLOTS 64
#define E_DIM   64
#define KEY_DIM 64
#define V_DIM   128
#define K_CAT   4
#define S_LEN   200

typedef __attribute__((ext_vector_type(8)))  short short8;
typedef __attribute__((ext_vector_type(16))) float f32x16;

// ---------------- ws layout (float offsets) ----------------
// Partials fully rewritten each call (no zeroing needed).
#define OFF_WSUMP  0                          // [S][4][64] = 51200
#define OFF_EMSUMP (S_LEN * 4 * M_SLOTS)      // [S][4] = 800

// pack two f32 -> bf16 pair, round-to-nearest-even (for MFMA inputs)
__device__ __forceinline__ unsigned pk2rne(float lo, float hi) {
    unsigned ul = __float_as_uint(lo); ul += 0x7fffu + ((ul >> 16) & 1u);
    unsigned uh = __float_as_uint(hi); uh += 0x7fffu + ((uh >> 16) & 1u);
    return __builtin_amdgcn_perm(uh, ul, 0x07060302u);
}
__device__ __forceinline__ short8 as_s8(uint4 u) { return __builtin_bit_cast(short8, u); }
__device__ __forceinline__ unsigned sx32(unsigned v) {
    return (unsigned)__shfl_xor((int)v, 32);
}

__device__ __forceinline__ void gpcm_store(float th, int q,
                                           const float* __restrict__ alpha_mean,
                                           const float* __restrict__ beta_base,
                                           const float* __restrict__ beta_gaps,
                                           float* __restrict__ out, size_t idx) {
    float a  = __expf(alpha_mean[q]);
    float b0 = beta_base[q];
    float2 g = *reinterpret_cast<const float2*>(&beta_gaps[q * (K_CAT - 2)]);
    float g0 = log1pf(__expf(g.x));
    float g1 = log1pf(__expf(g.y));
    float be1 = b0 + g0;
    float be2 = be1 + g1;
    float z0 = a * (th - b0);
    float z1 = a * (th - be1);
    float z2 = a * (th - be2);
    float c1 = z0, c2 = z0 + z1, c3 = z0 + z1 + z2;
    float cm = fmaxf(fmaxf(0.f, c1), fmaxf(c2, c3));
    float e0 = __expf(0.f - cm), e1 = __expf(c1 - cm), e2 = __expf(c2 - cm), e3 = __expf(c3 - cm);
    float si = __fdividef(1.0f, e0 + e1 + e2 + e3);
    float4 o4 = make_float4(e0 * si, e1 * si, e2 * si, e3 * si);
    *reinterpret_cast<float4*>(&out[idx * K_CAT]) = o4;
}

// Gather the lane's q-row slices (issue early to hide latency).
__device__ __forceinline__ void load_qf(const float* __restrict__ qrow, int h, float4 qf[8]) {
    #pragma unroll
    for (int s = 0; s < 4; ++s) {
        const float4* src = (const float4*)(qrow + s * 16 + h * 8);
        qf[2 * s]     = src[0];
        qf[2 * s + 1] = src[1];
    }
}

// Two-stage MFMA logits (no precomputed Ct):
//   stage1: query[key][pair] = q2k_w^T . qrow + q2k_b   (bias in C-operand)
//   glue:   D1 fragments -> stage2 B fragments via shfl_xor(32) half-exchange
//   stage2: logit[m][pair] = mkeys . query
// Final D layout identical to the old path: m = (j&3)+8*((j>>2)&3)+4h+32mt, col p.
__device__ __forceinline__ void mfma_logits2(
    const float4 qf[8],
    const float* __restrict__ q2k_w, const float* __restrict__ q2k_b,
    const float* __restrict__ mkeys,
    int h, int p, f32x16 acc[2])
{
    // ---- stage 1 ----
    f32x16 a1[2];
    #pragma unroll
    for (int kt = 0; kt < 2; ++kt)
        #pragma unroll
        for (int j = 0; j < 16; ++j)
            a1[kt][j] = q2k_b[kt * 32 + (j & 3) + 8 * ((j >> 2) & 3) + 4 * h];
    #pragma unroll
    for (int s1 = 0; s1 < 4; ++s1) {
        uint4 bu;
        bu.x = pk2rne(qf[2 * s1].x,     qf[2 * s1].y);
        bu.y = pk2rne(qf[2 * s1].z,     qf[2 * s1].w);
        bu.z = pk2rne(qf[2 * s1 + 1].x, qf[2 * s1 + 1].y);
        bu.w = pk2rne(qf[2 * s1 + 1].z, qf[2 * s1 + 1].w);
        short8 b1 = as_s8(bu);
        #pragma unroll
        for (int kt = 0; kt < 2; ++kt) {
            // A1[key = p+32kt][e = s1*16 + h*8 + u] = q2k_w[e*64 + key] (stride-64 column)
            const float* wc = q2k_w + (s1 * 16 + h * 8) * 64 + kt * 32 + p;
            uint4 au;
            au.x = pk2rne(wc[0],   wc[64]);
            au.y = pk2rne(wc[128], wc[192]);
            au.z = pk2rne(wc[256], wc[320]);
            au.w = pk2rne(wc[384], wc[448]);
            a1[kt] = __builtin_amdgcn_mfma_f32_32x32x16_bf16(as_s8(au), b1, a1[kt], 0, 0, 0);
        }
    }
    // ---- glue: build stage2 B-frags ----
    short8 b2[4];
    #pragma unroll
    for (int kt = 0; kt < 2; ++kt) {
        f32x16 d = a1[kt];
        unsigned w01 = pk2rne(d[0], d[1]),   w23 = pk2rne(d[2], d[3]);
        unsigned w45 = pk2rne(d[4], d[5]),   w67 = pk2rne(d[6], d[7]);
        unsigned v01 = pk2rne(d[8], d[9]),   v23 = pk2rne(d[10], d[11]);
        unsigned v45 = pk2rne(d[12], d[13]), v67 = pk2rne(d[14], d[15]);
        unsigned x01 = sx32(w01), x23 = sx32(w23), x45 = sx32(w45), x67 = sx32(w67);
        unsigned y01 = sx32(v01), y23 = sx32(v23), y45 = sx32(v45), y67 = sx32(v67);
        uint4 f0, f1;
        f0.x = h ? x45 : w01; f0.y = h ? x67 : w23; f0.z = h ? w45 : x01; f0.w = h ? w67 : x23;
        f1.x = h ? y45 : v01; f1.y = h ? y67 : v23; f1.z = h ? v45 : y01; f1.w = h ? v67 : y23;
        b2[kt * 2]     = as_s8(f0);
        b2[kt * 2 + 1] = as_s8(f1);
    }
    // ---- stage 2 ----
    #pragma unroll
    for (int mt = 0; mt < 2; ++mt)
        #pragma unroll
        for (int j = 0; j < 16; ++j) acc[mt][j] = 0.f;
    #pragma unroll
    for (int s = 0; s < 4; ++s) {
        #pragma unroll
        for (int mt = 0; mt < 2; ++mt) {
            const float* mr = mkeys + (p + 32 * mt) * 64 + s * 16 + h * 8;
            float4 m0 = *(const float4*)mr, m1 = *(const float4*)(mr + 4);
            uint4 au;
            au.x = pk2rne(m0.x, m0.y); au.y = pk2rne(m0.z, m0.w);
            au.z = pk2rne(m1.x, m1.y); au.w = pk2rne(m1.z, m1.w);
            acc[mt] = __builtin_amdgcn_mfma_f32_32x32x16_bf16(as_s8(au), b2[s], acc[mt], 0, 0, 0);
        }
    }
}

// K1: stats. Grid (S, B/128). 2-stage logits, softmax, fold, per-block partial stores.
__global__ __launch_bounds__(256, 3) void k_attn(
    const float* __restrict__ qtab, const int* __restrict__ qs, const int* __restrict__ rs,
    const float* __restrict__ q2k_w, const float* __restrict__ q2k_b,
    const float* __restrict__ mkeys,
    const float* __restrict__ qa_w, const float* __restrict__ qa_b,
    const float* __restrict__ ev_w, const float* __restrict__ ev_b,
    float* __restrict__ wsum_p, float* __restrict__ emsum_p,
    int B, float invNQ)
{
    __shared__ float4 lsEv[64];
    __shared__ float lsBB;
    __shared__ float lsFold[4][M_SLOTS];
    __shared__ float lsEvw[4];
    const int tid = threadIdx.x, wv = tid >> 6, lane = tid & 63;
    const int h = lane >> 5, p = lane & 31;
    const int t = blockIdx.x, by = blockIdx.y;
    const int b = by * 128 + wv * 32 + p;

    const int q = qs[(size_t)b * S_LEN + t];
    const int r = rs[(size_t)b * S_LEN + t];
    float4 qf[8];
    load_qf(qtab + (size_t)q * E_DIM, h, qf);   // issue gather early

    if (wv == 0) {   // lsEv[e] = (qa_w0, qa_w1, qa_b, rowmean ev_w[e])
        float wb = 0.f;
        const float4* er = (const float4*)(ev_w + (size_t)lane * V_DIM);
        #pragma unroll
        for (int i = 0; i < V_DIM / 4; ++i) {
            float4 v = er[i];
            wb += (v.x + v.y) + (v.z + v.w);
        }
        lsEv[lane] = make_float4(qa_w[lane], qa_w[E_DIM + lane], qa_b[lane],
                                 wb * (1.0f / V_DIM));
    } else if (wv == 1) {   // bbar
        float bbv = ev_b[lane] + ev_b[64 + lane];
        #pragma unroll
        for (int o = 32; o; o >>= 1) bbv += __shfl_xor(bbv, o);
        if (!lane) lsBB = bbv * (1.0f / V_DIM);
    }

    f32x16 acc[2];
    mfma_logits2(qf, q2k_w, q2k_b, mkeys, h, p, acc);

    // softmax over 64 slots of pair p (half h holds 32)
    float av[32];
    float ssum = 0.f;
    #pragma unroll
    for (int j = 0; j < 16; ++j) { av[j]      = __expf(acc[0][j]); ssum += av[j]; }
    #pragma unroll
    for (int j = 0; j < 16; ++j) { av[16 + j] = __expf(acc[1][j]); ssum += av[16 + j]; }
    ssum += __shfl_xor(ssum, 32);
    const float inv = __fdividef(1.0f, ssum);

    // fold normalized attn over 32 pairs (within half); lane ends with j=lane&31
    #pragma unroll
    for (int j = 0; j < 32; ++j) av[j] *= inv;
    #pragma unroll
    for (int step = 0; step < 5; ++step) {
        const int sh = 1 << step;
        #pragma unroll
        for (int j = 0; j < (32 >> step) / 2; ++j) {
            float p0 = av[2 * j]     + __shfl_xor(av[2 * j], sh);
            float p1 = av[2 * j + 1] + __shfl_xor(av[2 * j + 1], sh);
            av[j] = (lane & sh) ? p1 : p0;
        }
    }
    {
        const int jj = lane & 31;
        const int m = (jj & 3) + 8 * ((jj >> 2) & 3) + 4 * h + 32 * (jj >> 4);
        lsFold[wv][m] = av[0];
    }
    __syncthreads();   // lsEv + lsBB + lsFold ready

    // evidence scalar per pair, folded over this wave's 32 pairs
    float qn = (float)q * invNQ;
    float rn = (float)r * (1.0f / (K_CAT - 1));
    float evm = 0.f;
    #pragma unroll 8
    for (int e = 0; e < 32; ++e) {
        float4 pv = lsEv[h * 32 + e];
        float qa = fmaf(qn, pv.x, fmaf(rn, pv.y, pv.z));
        float ez = __expf(2.0f * qa);
        evm = fmaf(__fdividef(ez - 1.0f, ez + 1.0f), pv.w, evm);
    }
    evm += __shfl_xor(evm, 32);
    evm += lsBB;
    #pragma unroll
    for (int o = 16; o; o >>= 1) evm += __shfl_xor(evm, o);
    if (!lane) lsEvw[wv] = evm;
    __syncthreads();

    if (wv == 0) {
        float s4 = lsFold[0][lane] + lsFold[1][lane] + lsFold[2][lane] + lsFold[3][lane];
        wsum_p[(size_t)(t * 4 + by) * M_SLOTS + lane] = s4;
        if (!lane) emsum_p[t * 4 + by] = (lsEvw[0] + lsEvw[1]) + (lsEvw[2] + lsEvw[3]);
    }
}

// K2: output. Prefix from 4 consecutive-line partials (4-wave associative split),
// 2-stage MFMA recompute, softmax, theta dot, GPCM.
__global__ __launch_bounds__(256, 3) void k_out(
    const float* __restrict__ qtab, const int* __restrict__ qs,
    const float* __restrict__ q2k_w, const float* __restrict__ q2k_b,
    const float* __restrict__ mkeys,
    const float* __restrict__ means, const float* __restrict__ logvars,
    const float* __restrict__ wsum_p, const float* __restrict__ emsum_p,
    const float* __restrict__ alpha_mean, const float* __restrict__ beta_base,
    const float* __restrict__ beta_gaps, float* __restrict__ out,
    int B, float invB)
{
    __shared__ float lsW[4][M_SLOTS], lsN[4][M_SLOTS];
    __shared__ float lsRm0[M_SLOTS], lsP0[M_SLOTS];
    __shared__ float lsRmP[M_SLOTS];
    const int tid = threadIdx.x, wv = tid >> 6, lane = tid & 63;
    const int h = lane >> 5, p = lane & 31;
    const int t = blockIdx.x, by = blockIdx.y;
    const int b = by * 128 + wv * 32 + p;

    const int q = qs[(size_t)b * S_LEN + t];
    float4 qf[8];
    load_qf(qtab + (size_t)q * E_DIM, h, qf);   // issue gather early

    if (wv == 2) {   // rm0/p0 rebuild (32 KB L2-hot)
        float s = 0.f;
        const float4* mr = (const float4*)(means + (size_t)lane * V_DIM);
        #pragma unroll
        for (int i = 0; i < V_DIM / 4; ++i) {
            float4 v = mr[i];
            s += (v.x + v.y) + (v.z + v.w);
        }
        lsRm0[lane] = s * (1.0f / V_DIM);
        lsP0[lane]  = __expf(-logvars[(size_t)lane * V_DIM]);  // row-uniform
    }

    // prefix partials: wave wv sums t-segment [s0,s1) over m=lane, 2-way unrolled
    {
        const int seg = (t + 3) >> 2;
        const int s0 = wv * seg, s1 = min(s0 + seg, t);
        float pw0 = 0.f, pn0 = 0.f, pw1 = 0.f, pn1 = 0.f;
        int s = s0;
        for (; s + 2 <= s1; s += 2) {
            const float* wp0 = wsum_p + (size_t)s * 4 * M_SLOTS + lane;
            const float* wp1 = wp0 + 4 * M_SLOTS;
            float w0 = (wp0[0] + wp0[M_SLOTS]) + (wp0[2 * M_SLOTS] + wp0[3 * M_SLOTS]);
            float w1 = (wp1[0] + wp1[M_SLOTS]) + (wp1[2 * M_SLOTS] + wp1[3 * M_SLOTS]);
            const float* ep = emsum_p + s * 4;
            float e0 = (ep[0] + ep[1]) + (ep[2] + ep[3]);
            float e1 = (ep[4] + ep[5]) + (ep[6] + ep[7]);
            pw0 += w0; pn0 = fmaf(e0, w0, pn0);
            pw1 += w1; pn1 = fmaf(e1, w1, pn1);
        }
        if (s < s1) {
            const float* wp = wsum_p + (size_t)s * 4 * M_SLOTS + lane;
            float w = (wp[0] + wp[M_SLOTS]) + (wp[2 * M_SLOTS] + wp[3 * M_SLOTS]);
            const float* ep = emsum_p + s * 4;
            float em = (ep[0] + ep[1]) + (ep[2] + ep[3]);
            pw0 += w; pn0 = fmaf(em, w, pn0);
        }
        lsW[wv][lane] = pw0 + pw1; lsN[wv][lane] = pn0 + pn1;
    }
    __syncthreads();
    if (tid < 64) {
        const int m = tid;
        float sw = lsW[0][m] + lsW[1][m] + lsW[2][m] + lsW[3][m];
        float sn = lsN[0][m] + lsN[1][m] + lsN[2][m] + lsN[3][m];
        float den = lsP0[m] + sw * invB;
        float num = fmaf(lsP0[m], lsRm0[m], sn * (invB * invB));
        // MFMA slot-permuted index (r8-verified): idx = h(m)*32 + mt(m)*16 + j(m)
        const int idx = ((m >> 2) & 1) * 32 + ((m >> 5) & 1) * 16 + (m & 3) + 4 * ((m >> 3) & 3);
        lsRmP[idx] = num / den;   // state BEFORE update at t
    }
    __syncthreads();

    f32x16 acc[2];
    mfma_logits2(qf, q2k_w, q2k_b, mkeys, h, p, acc);

    float ssum = 0.f, th = 0.f;
    const float* rmh = lsRmP + h * 32;
    #pragma unroll
    for (int j = 0; j < 16; ++j) {
        float e = __expf(acc[0][j]);
        ssum += e;
        th = fmaf(e, rmh[j], th);
    }
    #pragma unroll
    for (int j = 0; j < 16; ++j) {
        float e = __expf(acc[1][j]);
        ssum += e;
        th = fmaf(e, rmh[16 + j], th);
    }
    ssum += __shfl_xor(ssum, 32);
    th   += __shfl_xor(th, 32);
    th = __fdividef(th, ssum);

    if (!h) gpcm_store(th, q, alpha_mean, beta_base, beta_gaps, out, (size_t)b * S_LEN + t);
}

extern "C" void kernel_launch(void* const* d_in, const int* in_sizes, int n_in,
                              void* d_out, int out_size, void* d_ws, size_t ws_size,
                              hipStream_t stream) {
    const float* qtab       = (const float*)d_in[0];
    const float* alpha_mean = (const float*)d_in[1];
    const float* beta_base  = (const float*)d_in[2];
    const float* beta_gaps  = (const float*)d_in[3];
    const float* ab_means   = (const float*)d_in[4];
    const float* ab_logvars = (const float*)d_in[5];
    const float* mkeys      = (const float*)d_in[6];
    const float* q2k_w      = (const float*)d_in[7];
    const float* q2k_b      = (const float*)d_in[8];
    const float* qa_w       = (const float*)d_in[9];
    const float* qa_b       = (const float*)d_in[10];
    const float* ev_w       = (const float*)d_in[11];
    const float* ev_b       = (const float*)d_in[12];
    const int*   qs         = (const int*)d_in[13];
    const int*   rs         = (const int*)d_in[14];
    float* out = (float*)d_out;
    float* ws  = (float*)d_ws;

    const int NQ = in_sizes[1];
    const int S  = S_LEN;
    const int B  = in_sizes[13] / S;   // 512

    float* wsum_p  = ws + OFF_WSUMP;
    float* emsum_p = ws + OFF_EMSUMP;

    dim3 g(S, B / 128);
    k_attn<<<g, 256, 0, stream>>>(qtab, qs, rs, q2k_w, q2k_b, mkeys,
                                  qa_w, qa_b, ev_w, ev_b,
                                  wsum_p, emsum_p, B, 1.0f / (float)NQ);

    k_out<<<g, 256, 0, stream>>>(qtab, qs, q2k_w, q2k_b, mkeys,
                                 ab_means, ab_logvars, wsum_p, emsum_p,
                                 alpha_mean, beta_base, beta_gaps, out,
                                 B, 1.0f / (float)B);
}

// Round 16
// 45.779 us; speedup vs baseline: 1.3411x; 1.3411x over previous
//
#include <hip/hip_runtime.h>
#include <math.h>

// Problem constants (from reference)
#define M_SLOTS 64
#define E_DIM   64
#define KEY_DIM 64
#define V_DIM   128
#define K_CAT   4
#define S_LEN   200

typedef __attribute__((ext_vector_type(8)))  short short8;
typedef __attribute__((ext_vector_type(16))) float f32x16;

// ---------------- ws layout (float offsets) ----------------
#define OFF_CT     0                          // 4096 ushort = 2048 f  (Ct[m][e] bf16)
#define OFF_BM     2048                       // 64
#define OFF_WBAR   2112                       // 64
#define OFF_BBAR   2176                       // 1
#define OFF_RM0    2240                       // 64
#define OFF_P0     2304                       // 64
#define OFF_WSUM   2368                       // S*M = 12800 (zeroed by k_pre blocks 1..13)
#define OFF_EMSUM  (OFF_WSUM + S_LEN*M_SLOTS) // 200 (contiguous w/ wsum)
#define ZERO_CNT   (S_LEN*M_SLOTS + S_LEN)    // 13000 floats

// pack two f32 -> bf16 pair, round-to-nearest-even (for MFMA inputs)
__device__ __forceinline__ unsigned pk2rne(float lo, float hi) {
    unsigned ul = __float_as_uint(lo); ul += 0x7fffu + ((ul >> 16) & 1u);
    unsigned uh = __float_as_uint(hi); uh += 0x7fffu + ((uh >> 16) & 1u);
    return __builtin_amdgcn_perm(uh, ul, 0x07060302u);
}
__device__ __forceinline__ unsigned short bf16rne(float f) {
    unsigned u = __float_as_uint(f);
    return (unsigned short)((u + 0x7fffu + ((u >> 16) & 1u)) >> 16);
}
__device__ __forceinline__ short8 as_s8(uint4 u) { return __builtin_bit_cast(short8, u); }

__device__ __forceinline__ void gpcm_store(float th, int q,
                                           const float* __restrict__ alpha_mean,
                                           const float* __restrict__ beta_base,
                                           const float* __restrict__ beta_gaps,
                                           float* __restrict__ out, size_t idx) {
    float a  = __expf(alpha_mean[q]);
    float b0 = beta_base[q];
    float2 g = *reinterpret_cast<const float2*>(&beta_gaps[q * (K_CAT - 2)]);
    float g0 = log1pf(__expf(g.x));
    float g1 = log1pf(__expf(g.y));
    float be1 = b0 + g0;
    float be2 = be1 + g1;
    float z0 = a * (th - b0);
    float z1 = a * (th - be1);
    float z2 = a * (th - be2);
    float c1 = z0, c2 = z0 + z1, c3 = z0 + z1 + z2;
    float cm = fmaxf(fmaxf(0.f, c1), fmaxf(c2, c3));
    float e0 = __expf(0.f - cm), e1 = __expf(c1 - cm), e2 = __expf(c2 - cm), e3 = __expf(c3 - cm);
    float si = __fdividef(1.0f, e0 + e1 + e2 + e3);
    float4 o4 = make_float4(e0 * si, e1 * si, e2 * si, e3 * si);
    *reinterpret_cast<float4*>(&out[idx * K_CAT]) = o4;
}

// Gather the lane's q-row slices (issue early to hide latency).
__device__ __forceinline__ void load_qf(const float* __restrict__ qrow, int h, float4 qf[8]) {
    #pragma unroll
    for (int s = 0; s < 4; ++s) {
        const float4* src = (const float4*)(qrow + s * 16 + h * 8);
        qf[2 * s]     = src[0];
        qf[2 * s + 1] = src[1];
    }
}

// 32x32x16 MFMA logits from preloaded qf: acc[mt][j] = logit for
// m = (j&3) + 8*((j>>2)&3) + 4*h + 32*mt, pair col p.
__device__ __forceinline__ void mfma_logits(
    const float4 qf[8], const unsigned short* __restrict__ ct,
    const float* __restrict__ bm, int h, int p, f32x16 acc[2])
{
    uint4 af[8];
    #pragma unroll
    for (int mt = 0; mt < 2; ++mt)
        #pragma unroll
        for (int s = 0; s < 4; ++s)
            af[mt * 4 + s] = *(const uint4*)(ct + (p + 32 * mt) * E_DIM + s * 16 + h * 8);
    #pragma unroll
    for (int mt = 0; mt < 2; ++mt)
        #pragma unroll
        for (int g = 0; g < 4; ++g) {
            float4 v = *(const float4*)(bm + 8 * g + 4 * h + 32 * mt);
            acc[mt][4 * g + 0] = v.x; acc[mt][4 * g + 1] = v.y;
            acc[mt][4 * g + 2] = v.z; acc[mt][4 * g + 3] = v.w;
        }
    #pragma unroll
    for (int s = 0; s < 4; ++s) {
        uint4 bf;
        bf.x = pk2rne(qf[2 * s].x,     qf[2 * s].y);
        bf.y = pk2rne(qf[2 * s].z,     qf[2 * s].w);
        bf.z = pk2rne(qf[2 * s + 1].x, qf[2 * s + 1].y);
        bf.w = pk2rne(qf[2 * s + 1].z, qf[2 * s + 1].w);
        short8 bfr = as_s8(bf);
        acc[0] = __builtin_amdgcn_mfma_f32_32x32x16_bf16(as_s8(af[s]),     bfr, acc[0], 0, 0, 0);
        acc[1] = __builtin_amdgcn_mfma_f32_32x32x16_bf16(as_s8(af[4 + s]), bfr, acc[1], 0, 0, 0);
    }
}

// softmax (64 slots, this lane holds 32) + pair-fold; adds partial into wsum atomics.
__device__ __forceinline__ void softmax_fold_store(
    const f32x16 acc[2], int lane, int h, int t,
    float* __restrict__ wsum)
{
    float av[32];
    float ssum = 0.f;
    #pragma unroll
    for (int j = 0; j < 16; ++j) { av[j]      = __expf(acc[0][j]); ssum += av[j]; }
    #pragma unroll
    for (int j = 0; j < 16; ++j) { av[16 + j] = __expf(acc[1][j]); ssum += av[16 + j]; }
    ssum += __shfl_xor(ssum, 32);
    const float inv = __fdividef(1.0f, ssum);
    #pragma unroll
    for (int j = 0; j < 32; ++j) av[j] *= inv;
    #pragma unroll
    for (int step = 0; step < 5; ++step) {
        const int sh = 1 << step;
        #pragma unroll
        for (int j = 0; j < (32 >> step) / 2; ++j) {
            float p0 = av[2 * j]     + __shfl_xor(av[2 * j], sh);
            float p1 = av[2 * j + 1] + __shfl_xor(av[2 * j + 1], sh);
            av[j] = (lane & sh) ? p1 : p0;
        }
    }
    const int jj = lane & 31;
    const int m = (jj & 3) + 8 * ((jj >> 2) & 3) + 4 * h + 32 * (jj >> 4);
    atomicAdd(&wsum[t * M_SLOTS + m], av[0]);
}

// k_pre: 14 blocks. Block 0: 4 waves, each one 32x32 Ct tile via MFMA + side
// duties. Blocks 1..13: zero wsum/emsum with float4 stores. (r14-verified)
__global__ __launch_bounds__(256) void k_pre(
    const float* __restrict__ q2k_w, const float* __restrict__ q2k_b,
    const float* __restrict__ mkeys,
    const float* __restrict__ ev_w, const float* __restrict__ ev_b,
    const float* __restrict__ means, const float* __restrict__ logvars,
    float* __restrict__ ws)
{
    const int tid = threadIdx.x;
    if (blockIdx.x != 0) {
        int i = ((int)blockIdx.x - 1) * 1024 + tid * 4;
        if (i + 4 <= ZERO_CNT) {
            *reinterpret_cast<float4*>(ws + OFF_WSUM + i) = make_float4(0.f, 0.f, 0.f, 0.f);
        } else {
            for (int j = i; j < ZERO_CNT; ++j) ws[OFF_WSUM + j] = 0.f;
        }
        return;
    }
    const int wv = tid >> 6, lane = tid & 63;
    const int h = lane >> 5, p = lane & 31;

    {
        const int m0 = (wv & 1) * 32, e0 = (wv >> 1) * 32;
        f32x16 d;
        #pragma unroll
        for (int i = 0; i < 16; ++i) d[i] = 0.f;
        #pragma unroll
        for (int s = 0; s < 4; ++s) {
            const float* ar = mkeys + (m0 + p) * KEY_DIM + s * 16 + h * 8;
            const float* br = q2k_w + (e0 + p) * KEY_DIM + s * 16 + h * 8;
            float4 a0 = *(const float4*)ar, a1 = *(const float4*)(ar + 4);
            float4 b0 = *(const float4*)br, b1 = *(const float4*)(br + 4);
            uint4 au, bu;
            au.x = pk2rne(a0.x, a0.y); au.y = pk2rne(a0.z, a0.w);
            au.z = pk2rne(a1.x, a1.y); au.w = pk2rne(a1.z, a1.w);
            bu.x = pk2rne(b0.x, b0.y); bu.y = pk2rne(b0.z, b0.w);
            bu.z = pk2rne(b1.x, b1.y); bu.w = pk2rne(b1.z, b1.w);
            d = __builtin_amdgcn_mfma_f32_32x32x16_bf16(as_s8(au), as_s8(bu), d, 0, 0, 0);
        }
        unsigned short* ct = (unsigned short*)ws;
        #pragma unroll
        for (int j = 0; j < 16; ++j) {
            int row = (j & 3) + 8 * ((j >> 2) & 3) + 4 * h;
            ct[(m0 + row) * E_DIM + e0 + p] = bf16rne(d[j]);
        }
    }

    if (wv == 0) {          // wbar[e]
        float s = 0.f;
        const float4* er = (const float4*)(ev_w + (size_t)lane * V_DIM);
        #pragma unroll
        for (int i = 0; i < V_DIM / 4; ++i) {
            float4 v = er[i];
            s += (v.x + v.y) + (v.z + v.w);
        }
        ws[OFF_WBAR + lane] = s * (1.0f / V_DIM);
    } else if (wv == 1) {   // bm, bbar
        float s = 0.f;
        const float4* mk = (const float4*)(mkeys + lane * KEY_DIM);
        const float4* qb = (const float4*)q2k_b;
        #pragma unroll
        for (int i = 0; i < KEY_DIM / 4; ++i) {
            float4 a = mk[i], c = qb[i];
            s += a.x * c.x + a.y * c.y + a.z * c.z + a.w * c.w;
        }
        ws[OFF_BM + lane] = s;
        float bbv = ev_b[lane] + ev_b[64 + lane];
        #pragma unroll
        for (int o = 32; o; o >>= 1) bbv += __shfl_xor(bbv, o);
        if (!lane) ws[OFF_BBAR] = bbv * (1.0f / V_DIM);
    } else if (wv == 2) {   // rm0/p0
        float s = 0.f;
        const float4* mr = (const float4*)(means + (size_t)lane * V_DIM);
        #pragma unroll
        for (int i = 0; i < V_DIM / 4; ++i) {
            float4 v = mr[i];
            s += (v.x + v.y) + (v.z + v.w);
        }
        ws[OFF_RM0 + lane] = s * (1.0f / V_DIM);
        ws[OFF_P0 + lane]  = __expf(-logvars[(size_t)lane * V_DIM]);  // row-uniform
    }
}

// Stats: 2 t's per block. Grid (S/2, B/128). Second t's qs/rs index is in the
// same cache line; both q-row gathers issue together (2x MLP).
__global__ __launch_bounds__(256, 3) void k_attn(
    const float* __restrict__ qtab, const int* __restrict__ qs, const int* __restrict__ rs,
    const float* __restrict__ ws_ro,
    const float* __restrict__ qa_w, const float* __restrict__ qa_b,
    float* __restrict__ wsum, float* __restrict__ emsum,
    int B, float invNQ)
{
    __shared__ float4 lsEv[64];
    const int tid = threadIdx.x, wv = tid >> 6, lane = tid & 63;
    const int h = lane >> 5, p = lane & 31;
    const int t0 = blockIdx.x * 2, t1 = t0 + 1;
    const int b = blockIdx.y * 128 + wv * 32 + p;

    const int q0 = qs[(size_t)b * S_LEN + t0];
    const int r0 = rs[(size_t)b * S_LEN + t0];
    const int q1 = qs[(size_t)b * S_LEN + t1];   // same line as t0
    const int r1 = rs[(size_t)b * S_LEN + t1];
    float4 qf0[8], qf1[8];
    load_qf(qtab + (size_t)q0 * E_DIM, h, qf0);  // both gathers in flight
    load_qf(qtab + (size_t)q1 * E_DIM, h, qf1);

    if (tid < 64) lsEv[tid] = make_float4(qa_w[tid], qa_w[E_DIM + tid], qa_b[tid],
                                          ws_ro[OFF_WBAR + tid]);
    const float bb = ws_ro[OFF_BBAR];

    {
        f32x16 acc[2];
        mfma_logits(qf0, (const unsigned short*)ws_ro, ws_ro + OFF_BM, h, p, acc);
        softmax_fold_store(acc, lane, h, t0, wsum);
    }
    {
        f32x16 acc[2];
        mfma_logits(qf1, (const unsigned short*)ws_ro, ws_ro + OFF_BM, h, p, acc);
        softmax_fold_store(acc, lane, h, t1, wsum);
    }

    __syncthreads();   // lsEv ready

    // evidence scalars for both t's
    float ev0 = 0.f, ev1 = 0.f;
    const float qn0 = (float)q0 * invNQ, rn0 = (float)r0 * (1.0f / (K_CAT - 1));
    const float qn1 = (float)q1 * invNQ, rn1 = (float)r1 * (1.0f / (K_CAT - 1));
    #pragma unroll 8
    for (int e = 0; e < 32; ++e) {
        float4 pv = lsEv[h * 32 + e];
        float qa0 = fmaf(qn0, pv.x, fmaf(rn0, pv.y, pv.z));
        float qa1 = fmaf(qn1, pv.x, fmaf(rn1, pv.y, pv.z));
        float ez0 = __expf(2.0f * qa0);
        float ez1 = __expf(2.0f * qa1);
        ev0 = fmaf(__fdividef(ez0 - 1.0f, ez0 + 1.0f), pv.w, ev0);
        ev1 = fmaf(__fdividef(ez1 - 1.0f, ez1 + 1.0f), pv.w, ev1);
    }
    ev0 += __shfl_xor(ev0, 32); ev0 += bb;
    ev1 += __shfl_xor(ev1, 32); ev1 += bb;
    #pragma unroll
    for (int o = 16; o; o >>= 1) { ev0 += __shfl_xor(ev0, o); ev1 += __shfl_xor(ev1, o); }
    if (!lane) {
        atomicAdd(&emsum[t0], ev0);
        atomicAdd(&emsum[t1], ev1);
    }
}

// Output: 2 t's per block. Prefix computed once for t0 (4-wave associative),
// t1's rm = t0's + one step. MFMA recompute + GPCM for both.
__global__ __launch_bounds__(256, 3) void k_out(
    const float* __restrict__ qtab, const int* __restrict__ qs,
    const float* __restrict__ ws_ro,
    const float* __restrict__ alpha_mean, const float* __restrict__ beta_base,
    const float* __restrict__ beta_gaps, float* __restrict__ out, int B, float invB)
{
    __shared__ float lsW[4][M_SLOTS], lsN[4][M_SLOTS];
    __shared__ float lsRmP0[M_SLOTS], lsRmP1[M_SLOTS];
    const int tid = threadIdx.x, wv = tid >> 6, lane = tid & 63;
    const int h = lane >> 5, p = lane & 31;
    const int t0 = blockIdx.x * 2, t1 = t0 + 1;
    const int b = blockIdx.y * 128 + wv * 32 + p;

    const int q0 = qs[(size_t)b * S_LEN + t0];
    const int q1 = qs[(size_t)b * S_LEN + t1];
    float4 qf0[8], qf1[8];
    load_qf(qtab + (size_t)q0 * E_DIM, h, qf0);  // issue gathers BEFORE prefix
    load_qf(qtab + (size_t)q1 * E_DIM, h, qf1);

    // prefix partials over [0, t0): wave wv sums its segment, 2-way unrolled
    {
        const float* wsum  = ws_ro + OFF_WSUM;
        const float* emsum = ws_ro + OFF_EMSUM;
        const int seg = (t0 + 3) >> 2;
        const int s0 = wv * seg, s1 = min(s0 + seg, t0);
        float pw0 = 0.f, pn0 = 0.f, pw1 = 0.f, pn1 = 0.f;
        int s = s0;
        for (; s + 2 <= s1; s += 2) {
            float w0 = wsum[s * M_SLOTS + lane];
            float w1 = wsum[(s + 1) * M_SLOTS + lane];
            float e0 = emsum[s], e1 = emsum[s + 1];
            pw0 += w0; pn0 = fmaf(e0, w0, pn0);
            pw1 += w1; pn1 = fmaf(e1, w1, pn1);
        }
        if (s < s1) {
            float w = wsum[s * M_SLOTS + lane];
            pw0 += w; pn0 = fmaf(emsum[s], w, pn0);
        }
        lsW[wv][lane] = pw0 + pw1; lsN[wv][lane] = pn0 + pn1;
    }
    __syncthreads();
    if (tid < 64) {
        const int m = tid;
        float sw = lsW[0][m] + lsW[1][m] + lsW[2][m] + lsW[3][m];
        float sn = lsN[0][m] + lsN[1][m] + lsN[2][m] + lsN[3][m];
        const float p0v = ws_ro[OFF_P0 + m];
        float den0 = p0v + sw * invB;
        float num0 = fmaf(p0v, ws_ro[OFF_RM0 + m], sn * (invB * invB));
        // one more step for t1: include stats of step t0
        float wstep = ws_ro[OFF_WSUM + t0 * M_SLOTS + m];
        float estep = ws_ro[OFF_EMSUM + t0];
        float den1 = den0 + wstep * invB;
        float num1 = fmaf(estep * wstep, invB * invB, num0);
        // MFMA slot-permuted index: idx = h(m)*32 + mt(m)*16 + j(m)
        const int idx = ((m >> 2) & 1) * 32 + ((m >> 5) & 1) * 16 + (m & 3) + 4 * ((m >> 3) & 3);
        lsRmP0[idx] = num0 / den0;
        lsRmP1[idx] = num1 / den1;
    }
    __syncthreads();

    #pragma unroll
    for (int it = 0; it < 2; ++it) {
        f32x16 acc[2];
        mfma_logits(it ? qf1 : qf0, (const unsigned short*)ws_ro, ws_ro + OFF_BM, h, p, acc);
        const float* rmh = (it ? lsRmP1 : lsRmP0) + h * 32;
        float ssum = 0.f, th = 0.f;
        #pragma unroll
        for (int j = 0; j < 16; ++j) {
            float e = __expf(acc[0][j]);
            ssum += e;
            th = fmaf(e, rmh[j], th);
        }
        #pragma unroll
        for (int j = 0; j < 16; ++j) {
            float e = __expf(acc[1][j]);
            ssum += e;
            th = fmaf(e, rmh[16 + j], th);
        }
        ssum += __shfl_xor(ssum, 32);
        th   += __shfl_xor(th, 32);
        th = __fdividef(th, ssum);
        if (!h) {
            const int t = it ? t1 : t0;
            const int q = it ? q1 : q0;
            gpcm_store(th, q, alpha_mean, beta_base, beta_gaps, out, (size_t)b * S_LEN + t);
        }
    }
}

extern "C" void kernel_launch(void* const* d_in, const int* in_sizes, int n_in,
                              void* d_out, int out_size, void* d_ws, size_t ws_size,
                              hipStream_t stream) {
    const float* qtab       = (const float*)d_in[0];
    const float* alpha_mean = (const float*)d_in[1];
    const float* beta_base  = (const float*)d_in[2];
    const float* beta_gaps  = (const float*)d_in[3];
    const float* ab_means   = (const float*)d_in[4];
    const float* ab_logvars = (const float*)d_in[5];
    const float* mkeys      = (const float*)d_in[6];
    const float* q2k_w      = (const float*)d_in[7];
    const float* q2k_b      = (const float*)d_in[8];
    const float* qa_w       = (const float*)d_in[9];
    const float* qa_b       = (const float*)d_in[10];
    const float* ev_w       = (const float*)d_in[11];
    const float* ev_b       = (const float*)d_in[12];
    const int*   qs         = (const int*)d_in[13];
    const int*   rs         = (const int*)d_in[14];
    float* out = (float*)d_out;
    float* ws  = (float*)d_ws;

    const int NQ = in_sizes[1];
    const int S  = S_LEN;
    const int B  = in_sizes[13] / S;   // 512

    float* wsum  = ws + OFF_WSUM;
    float* emsum = ws + OFF_EMSUM;

    k_pre<<<14, 256, 0, stream>>>(q2k_w, q2k_b, mkeys, ev_w, ev_b,
                                  ab_means, ab_logvars, ws);

    dim3 g(S / 2, B / 128);
    k_attn<<<g, 256, 0, stream>>>(qtab, qs, rs, ws, qa_w, qa_b,
                                  wsum, emsum, B, 1.0f / (float)NQ);

    k_out<<<g, 256, 0, stream>>>(qtab, qs, ws, alpha_mean, beta_base,
                                 beta_gaps, out, B, 1.0f / (float)B);
}

// Round 17
// 45.110 us; speedup vs baseline: 1.3610x; 1.0148x over previous
//
#include <hip/hip_runtime.h>
#include <math.h>

// Problem constants (from reference)
#define M_SLOTS 64
#define E_DIM   64
#define KEY_DIM 64
#define V_DIM   128
#define K_CAT   4
#define S_LEN   200

typedef __attribute__((ext_vector_type(8)))  short short8;
typedef __attribute__((ext_vector_type(16))) float f32x16;

// ---------------- ws layout (float offsets) ----------------
#define OFF_CT     0                          // 4096 ushort = 2048 f  (Ct[m][e] bf16)
#define OFF_BM     2048                       // 64
#define OFF_WBAR   2112                       // 64
#define OFF_BBAR   2176                       // 1
#define OFF_RM0    2240                       // 64
#define OFF_P0     2304                       // 64
#define OFF_WSUM   2368                       // S*M = 12800 (zeroed by k_pre blocks 1..13)
#define OFF_EMSUM  (OFF_WSUM + S_LEN*M_SLOTS) // 200 (contiguous w/ wsum)
#define ZERO_CNT   (S_LEN*M_SLOTS + S_LEN)    // 13000 floats

// pack two f32 -> bf16 pair, round-to-nearest-even (for MFMA inputs)
__device__ __forceinline__ unsigned pk2rne(float lo, float hi) {
    unsigned ul = __float_as_uint(lo); ul += 0x7fffu + ((ul >> 16) & 1u);
    unsigned uh = __float_as_uint(hi); uh += 0x7fffu + ((uh >> 16) & 1u);
    return __builtin_amdgcn_perm(uh, ul, 0x07060302u);
}
__device__ __forceinline__ unsigned short bf16rne(float f) {
    unsigned u = __float_as_uint(f);
    return (unsigned short)((u + 0x7fffu + ((u >> 16) & 1u)) >> 16);
}
__device__ __forceinline__ short8 as_s8(uint4 u) { return __builtin_bit_cast(short8, u); }

__device__ __forceinline__ void gpcm_store(float th, int q,
                                           const float* __restrict__ alpha_mean,
                                           const float* __restrict__ beta_base,
                                           const float* __restrict__ beta_gaps,
                                           float* __restrict__ out, size_t idx) {
    float a  = __expf(alpha_mean[q]);
    float b0 = beta_base[q];
    float2 g = *reinterpret_cast<const float2*>(&beta_gaps[q * (K_CAT - 2)]);
    float g0 = log1pf(__expf(g.x));
    float g1 = log1pf(__expf(g.y));
    float be1 = b0 + g0;
    float be2 = be1 + g1;
    float z0 = a * (th - b0);
    float z1 = a * (th - be1);
    float z2 = a * (th - be2);
    float c1 = z0, c2 = z0 + z1, c3 = z0 + z1 + z2;
    float cm = fmaxf(fmaxf(0.f, c1), fmaxf(c2, c3));
    float e0 = __expf(0.f - cm), e1 = __expf(c1 - cm), e2 = __expf(c2 - cm), e3 = __expf(c3 - cm);
    float si = __fdividef(1.0f, e0 + e1 + e2 + e3);
    float4 o4 = make_float4(e0 * si, e1 * si, e2 * si, e3 * si);
    *reinterpret_cast<float4*>(&out[idx * K_CAT]) = o4;
}

// Gather the lane's q-row slices (issue early to hide latency).
__device__ __forceinline__ void load_qf(const float* __restrict__ qrow, int h, float4 qf[8]) {
    #pragma unroll
    for (int s = 0; s < 4; ++s) {
        const float4* src = (const float4*)(qrow + s * 16 + h * 8);
        qf[2 * s]     = src[0];
        qf[2 * s + 1] = src[1];
    }
}

// Load the lane's 8 Ct A-fragments once (t-invariant).
__device__ __forceinline__ void load_afrags(const unsigned short* __restrict__ ct,
                                            int h, int p, uint4 af[8]) {
    #pragma unroll
    for (int mt = 0; mt < 2; ++mt)
        #pragma unroll
        for (int s = 0; s < 4; ++s)
            af[mt * 4 + s] = *(const uint4*)(ct + (p + 32 * mt) * E_DIM + s * 16 + h * 8);
}

// 32x32x16 MFMA logits from preloaded qf + af: acc[mt][j] = logit for
// m = (j&3) + 8*((j>>2)&3) + 4*h + 32*mt, pair col p.
__device__ __forceinline__ void mfma_logits(
    const float4 qf[8], const uint4 af[8],
    const float* __restrict__ bm, int h, f32x16 acc[2])
{
    #pragma unroll
    for (int mt = 0; mt < 2; ++mt)
        #pragma unroll
        for (int g = 0; g < 4; ++g) {
            float4 v = *(const float4*)(bm + 8 * g + 4 * h + 32 * mt);
            acc[mt][4 * g + 0] = v.x; acc[mt][4 * g + 1] = v.y;
            acc[mt][4 * g + 2] = v.z; acc[mt][4 * g + 3] = v.w;
        }
    #pragma unroll
    for (int s = 0; s < 4; ++s) {
        uint4 bf;
        bf.x = pk2rne(qf[2 * s].x,     qf[2 * s].y);
        bf.y = pk2rne(qf[2 * s].z,     qf[2 * s].w);
        bf.z = pk2rne(qf[2 * s + 1].x, qf[2 * s + 1].y);
        bf.w = pk2rne(qf[2 * s + 1].z, qf[2 * s + 1].w);
        short8 bfr = as_s8(bf);
        acc[0] = __builtin_amdgcn_mfma_f32_32x32x16_bf16(as_s8(af[s]),     bfr, acc[0], 0, 0, 0);
        acc[1] = __builtin_amdgcn_mfma_f32_32x32x16_bf16(as_s8(af[4 + s]), bfr, acc[1], 0, 0, 0);
    }
}

// softmax (64 slots, this lane holds 32) + pair-fold; adds partial into wsum atomics.
__device__ __forceinline__ void softmax_fold_store(
    const f32x16 acc[2], int lane, int h, int t,
    float* __restrict__ wsum)
{
    float av[32];
    float ssum = 0.f;
    #pragma unroll
    for (int j = 0; j < 16; ++j) { av[j]      = __expf(acc[0][j]); ssum += av[j]; }
    #pragma unroll
    for (int j = 0; j < 16; ++j) { av[16 + j] = __expf(acc[1][j]); ssum += av[16 + j]; }
    ssum += __shfl_xor(ssum, 32);
    const float inv = __fdividef(1.0f, ssum);
    #pragma unroll
    for (int j = 0; j < 32; ++j) av[j] *= inv;
    #pragma unroll
    for (int step = 0; step < 5; ++step) {
        const int sh = 1 << step;
        #pragma unroll
        for (int j = 0; j < (32 >> step) / 2; ++j) {
            float p0 = av[2 * j]     + __shfl_xor(av[2 * j], sh);
            float p1 = av[2 * j + 1] + __shfl_xor(av[2 * j + 1], sh);
            av[j] = (lane & sh) ? p1 : p0;
        }
    }
    const int jj = lane & 31;
    const int m = (jj & 3) + 8 * ((jj >> 2) & 3) + 4 * h + 32 * (jj >> 4);
    atomicAdd(&wsum[t * M_SLOTS + m], av[0]);
}

// k_pre: 14 blocks. Block 0: 4 waves, each one 32x32 Ct tile via MFMA + side
// duties. Blocks 1..13: zero wsum/emsum with float4 stores. (r14-verified)
__global__ __launch_bounds__(256) void k_pre(
    const float* __restrict__ q2k_w, const float* __restrict__ q2k_b,
    const float* __restrict__ mkeys,
    const float* __restrict__ ev_w, const float* __restrict__ ev_b,
    const float* __restrict__ means, const float* __restrict__ logvars,
    float* __restrict__ ws)
{
    const int tid = threadIdx.x;
    if (blockIdx.x != 0) {
        int i = ((int)blockIdx.x - 1) * 1024 + tid * 4;
        if (i + 4 <= ZERO_CNT) {
            *reinterpret_cast<float4*>(ws + OFF_WSUM + i) = make_float4(0.f, 0.f, 0.f, 0.f);
        } else {
            for (int j = i; j < ZERO_CNT; ++j) ws[OFF_WSUM + j] = 0.f;
        }
        return;
    }
    const int wv = tid >> 6, lane = tid & 63;
    const int h = lane >> 5, p = lane & 31;

    {
        const int m0 = (wv & 1) * 32, e0 = (wv >> 1) * 32;
        f32x16 d;
        #pragma unroll
        for (int i = 0; i < 16; ++i) d[i] = 0.f;
        #pragma unroll
        for (int s = 0; s < 4; ++s) {
            const float* ar = mkeys + (m0 + p) * KEY_DIM + s * 16 + h * 8;
            const float* br = q2k_w + (e0 + p) * KEY_DIM + s * 16 + h * 8;
            float4 a0 = *(const float4*)ar, a1 = *(const float4*)(ar + 4);
            float4 b0 = *(const float4*)br, b1 = *(const float4*)(br + 4);
            uint4 au, bu;
            au.x = pk2rne(a0.x, a0.y); au.y = pk2rne(a0.z, a0.w);
            au.z = pk2rne(a1.x, a1.y); au.w = pk2rne(a1.z, a1.w);
            bu.x = pk2rne(b0.x, b0.y); bu.y = pk2rne(b0.z, b0.w);
            bu.z = pk2rne(b1.x, b1.y); bu.w = pk2rne(b1.z, b1.w);
            d = __builtin_amdgcn_mfma_f32_32x32x16_bf16(as_s8(au), as_s8(bu), d, 0, 0, 0);
        }
        unsigned short* ct = (unsigned short*)ws;
        #pragma unroll
        for (int j = 0; j < 16; ++j) {
            int row = (j & 3) + 8 * ((j >> 2) & 3) + 4 * h;
            ct[(m0 + row) * E_DIM + e0 + p] = bf16rne(d[j]);
        }
    }

    if (wv == 0) {          // wbar[e]
        float s = 0.f;
        const float4* er = (const float4*)(ev_w + (size_t)lane * V_DIM);
        #pragma unroll
        for (int i = 0; i < V_DIM / 4; ++i) {
            float4 v = er[i];
            s += (v.x + v.y) + (v.z + v.w);
        }
        ws[OFF_WBAR + lane] = s * (1.0f / V_DIM);
    } else if (wv == 1) {   // bm, bbar
        float s = 0.f;
        const float4* mk = (const float4*)(mkeys + lane * KEY_DIM);
        const float4* qb = (const float4*)q2k_b;
        #pragma unroll
        for (int i = 0; i < KEY_DIM / 4; ++i) {
            float4 a = mk[i], c = qb[i];
            s += a.x * c.x + a.y * c.y + a.z * c.z + a.w * c.w;
        }
        ws[OFF_BM + lane] = s;
        float bbv = ev_b[lane] + ev_b[64 + lane];
        #pragma unroll
        for (int o = 32; o; o >>= 1) bbv += __shfl_xor(bbv, o);
        if (!lane) ws[OFF_BBAR] = bbv * (1.0f / V_DIM);
    } else if (wv == 2) {   // rm0/p0
        float s = 0.f;
        const float4* mr = (const float4*)(means + (size_t)lane * V_DIM);
        #pragma unroll
        for (int i = 0; i < V_DIM / 4; ++i) {
            float4 v = mr[i];
            s += (v.x + v.y) + (v.z + v.w);
        }
        ws[OFF_RM0 + lane] = s * (1.0f / V_DIM);
        ws[OFF_P0 + lane]  = __expf(-logvars[(size_t)lane * V_DIM]);  // row-uniform
    }
}

// Stats: 2 t's per block. Grid (S/2, B/128). A-frags hoisted across both t's.
__global__ __launch_bounds__(256, 3) void k_attn(
    const float* __restrict__ qtab, const int* __restrict__ qs, const int* __restrict__ rs,
    const float* __restrict__ ws_ro,
    const float* __restrict__ qa_w, const float* __restrict__ qa_b,
    float* __restrict__ wsum, float* __restrict__ emsum,
    int B, float invNQ)
{
    __shared__ float4 lsEv[64];
    const int tid = threadIdx.x, wv = tid >> 6, lane = tid & 63;
    const int h = lane >> 5, p = lane & 31;
    const int t0 = blockIdx.x * 2, t1 = t0 + 1;
    const int b = blockIdx.y * 128 + wv * 32 + p;

    const int q0 = qs[(size_t)b * S_LEN + t0];
    const int r0 = rs[(size_t)b * S_LEN + t0];
    const int q1 = qs[(size_t)b * S_LEN + t1];   // same line as t0
    const int r1 = rs[(size_t)b * S_LEN + t1];
    float4 qf0[8], qf1[8];
    load_qf(qtab + (size_t)q0 * E_DIM, h, qf0);  // both gathers in flight
    load_qf(qtab + (size_t)q1 * E_DIM, h, qf1);

    uint4 af[8];
    load_afrags((const unsigned short*)ws_ro, h, p, af);   // t-invariant

    if (tid < 64) lsEv[tid] = make_float4(qa_w[tid], qa_w[E_DIM + tid], qa_b[tid],
                                          ws_ro[OFF_WBAR + tid]);
    const float bb = ws_ro[OFF_BBAR];

    {
        f32x16 acc[2];
        mfma_logits(qf0, af, ws_ro + OFF_BM, h, acc);
        softmax_fold_store(acc, lane, h, t0, wsum);
    }
    {
        f32x16 acc[2];
        mfma_logits(qf1, af, ws_ro + OFF_BM, h, acc);
        softmax_fold_store(acc, lane, h, t1, wsum);
    }

    __syncthreads();   // lsEv ready

    // evidence scalars for both t's
    float ev0 = 0.f, ev1 = 0.f;
    const float qn0 = (float)q0 * invNQ, rn0 = (float)r0 * (1.0f / (K_CAT - 1));
    const float qn1 = (float)q1 * invNQ, rn1 = (float)r1 * (1.0f / (K_CAT - 1));
    #pragma unroll 8
    for (int e = 0; e < 32; ++e) {
        float4 pv = lsEv[h * 32 + e];
        float qa0 = fmaf(qn0, pv.x, fmaf(rn0, pv.y, pv.z));
        float qa1 = fmaf(qn1, pv.x, fmaf(rn1, pv.y, pv.z));
        float ez0 = __expf(2.0f * qa0);
        float ez1 = __expf(2.0f * qa1);
        ev0 = fmaf(__fdividef(ez0 - 1.0f, ez0 + 1.0f), pv.w, ev0);
        ev1 = fmaf(__fdividef(ez1 - 1.0f, ez1 + 1.0f), pv.w, ev1);
    }
    ev0 += __shfl_xor(ev0, 32); ev0 += bb;
    ev1 += __shfl_xor(ev1, 32); ev1 += bb;
    #pragma unroll
    for (int o = 16; o; o >>= 1) { ev0 += __shfl_xor(ev0, o); ev1 += __shfl_xor(ev1, o); }
    if (!lane) {
        atomicAdd(&emsum[t0], ev0);
        atomicAdd(&emsum[t1], ev1);
    }
}

// Output: 2 t's per block. Prefix computed once for t0 (4-wave associative),
// t1's rm = t0's + one step. A-frags hoisted; MFMA recompute + GPCM for both.
__global__ __launch_bounds__(256, 3) void k_out(
    const float* __restrict__ qtab, const int* __restrict__ qs,
    const float* __restrict__ ws_ro,
    const float* __restrict__ alpha_mean, const float* __restrict__ beta_base,
    const float* __restrict__ beta_gaps, float* __restrict__ out, int B, float invB)
{
    __shared__ float lsW[4][M_SLOTS], lsN[4][M_SLOTS];
    __shared__ float lsRmP0[M_SLOTS], lsRmP1[M_SLOTS];
    const int tid = threadIdx.x, wv = tid >> 6, lane = tid & 63;
    const int h = lane >> 5, p = lane & 31;
    const int t0 = blockIdx.x * 2, t1 = t0 + 1;
    const int b = blockIdx.y * 128 + wv * 32 + p;

    const int q0 = qs[(size_t)b * S_LEN + t0];
    const int q1 = qs[(size_t)b * S_LEN + t1];
    float4 qf0[8], qf1[8];
    load_qf(qtab + (size_t)q0 * E_DIM, h, qf0);  // issue gathers BEFORE prefix
    load_qf(qtab + (size_t)q1 * E_DIM, h, qf1);

    uint4 af[8];
    load_afrags((const unsigned short*)ws_ro, h, p, af);   // t-invariant

    // prefix partials over [0, t0): wave wv sums its segment, 2-way unrolled
    {
        const float* wsum  = ws_ro + OFF_WSUM;
        const float* emsum = ws_ro + OFF_EMSUM;
        const int seg = (t0 + 3) >> 2;
        const int s0 = wv * seg, s1 = min(s0 + seg, t0);
        float pw0 = 0.f, pn0 = 0.f, pw1 = 0.f, pn1 = 0.f;
        int s = s0;
        for (; s + 2 <= s1; s += 2) {
            float w0 = wsum[s * M_SLOTS + lane];
            float w1 = wsum[(s + 1) * M_SLOTS + lane];
            float e0 = emsum[s], e1 = emsum[s + 1];
            pw0 += w0; pn0 = fmaf(e0, w0, pn0);
            pw1 += w1; pn1 = fmaf(e1, w1, pn1);
        }
        if (s < s1) {
            float w = wsum[s * M_SLOTS + lane];
            pw0 += w; pn0 = fmaf(emsum[s], w, pn0);
        }
        lsW[wv][lane] = pw0 + pw1; lsN[wv][lane] = pn0 + pn1;
    }
    __syncthreads();
    if (tid < 64) {
        const int m = tid;
        float sw = lsW[0][m] + lsW[1][m] + lsW[2][m] + lsW[3][m];
        float sn = lsN[0][m] + lsN[1][m] + lsN[2][m] + lsN[3][m];
        const float p0v = ws_ro[OFF_P0 + m];
        float den0 = p0v + sw * invB;
        float num0 = fmaf(p0v, ws_ro[OFF_RM0 + m], sn * (invB * invB));
        // one more step for t1: include stats of step t0
        float wstep = ws_ro[OFF_WSUM + t0 * M_SLOTS + m];
        float estep = ws_ro[OFF_EMSUM + t0];
        float den1 = den0 + wstep * invB;
        float num1 = fmaf(estep * wstep, invB * invB, num0);
        // MFMA slot-permuted index: idx = h(m)*32 + mt(m)*16 + j(m)
        const int idx = ((m >> 2) & 1) * 32 + ((m >> 5) & 1) * 16 + (m & 3) + 4 * ((m >> 3) & 3);
        lsRmP0[idx] = num0 / den0;
        lsRmP1[idx] = num1 / den1;
    }
    __syncthreads();

    #pragma unroll
    for (int it = 0; it < 2; ++it) {
        f32x16 acc[2];
        mfma_logits(it ? qf1 : qf0, af, ws_ro + OFF_BM, h, acc);
        const float* rmh = (it ? lsRmP1 : lsRmP0) + h * 32;
        float ssum = 0.f, th = 0.f;
        #pragma unroll
        for (int j = 0; j < 16; ++j) {
            float e = __expf(acc[0][j]);
            ssum += e;
            th = fmaf(e, rmh[j], th);
        }
        #pragma unroll
        for (int j = 0; j < 16; ++j) {
            float e = __expf(acc[1][j]);
            ssum += e;
            th = fmaf(e, rmh[16 + j], th);
        }
        ssum += __shfl_xor(ssum, 32);
        th   += __shfl_xor(th, 32);
        th = __fdividef(th, ssum);
        if (!h) {
            const int t = it ? t1 : t0;
            const int q = it ? q1 : q0;
            gpcm_store(th, q, alpha_mean, beta_base, beta_gaps, out, (size_t)b * S_LEN + t);
        }
    }
}

extern "C" void kernel_launch(void* const* d_in, const int* in_sizes, int n_in,
                              void* d_out, int out_size, void* d_ws, size_t ws_size,
                              hipStream_t stream) {
    const float* qtab       = (const float*)d_in[0];
    const float* alpha_mean = (const float*)d_in[1];
    const float* beta_base  = (const float*)d_in[2];
    const float* beta_gaps  = (const float*)d_in[3];
    const float* ab_means   = (const float*)d_in[4];
    const float* ab_logvars = (const float*)d_in[5];
    const float* mkeys      = (const float*)d_in[6];
    const float* q2k_w      = (const float*)d_in[7];
    const float* q2k_b      = (const float*)d_in[8];
    const float* qa_w       = (const float*)d_in[9];
    const float* qa_b       = (const float*)d_in[10];
    const float* ev_w       = (const float*)d_in[11];
    const float* ev_b       = (const float*)d_in[12];
    const int*   qs         = (const int*)d_in[13];
    const int*   rs         = (const int*)d_in[14];
    float* out = (float*)d_out;
    float* ws  = (float*)d_ws;

    const int NQ = in_sizes[1];
    const int S  = S_LEN;
    const int B  = in_sizes[13] / S;   // 512

    float* wsum  = ws + OFF_WSUM;
    float* emsum = ws + OFF_EMSUM;

    k_pre<<<14, 256, 0, stream>>>(q2k_w, q2k_b, mkeys, ev_w, ev_b,
                                  ab_means, ab_logvars, ws);

    dim3 g(S / 2, B / 128);
    k_attn<<<g, 256, 0, stream>>>(qtab, qs, rs, ws, qa_w, qa_b,
                                  wsum, emsum, B, 1.0f / (float)NQ);

    k_out<<<g, 256, 0, stream>>>(qtab, qs, ws, alpha_mean, beta_base,
                                 beta_gaps, out, B, 1.0f / (float)B);
}

// Round 18
// 44.352 us; speedup vs baseline: 1.3843x; 1.0171x over previous
//
#include <hip/hip_runtime.h>
#include <math.h>

// Problem constants (from reference)
#define M_SLOTS 64
#define E_DIM   64
#define KEY_DIM 64
#define V_DIM   128
#define K_CAT   4
#define S_LEN   200

typedef __attribute__((ext_vector_type(8)))  short short8;
typedef __attribute__((ext_vector_type(16))) float f32x16;

// ---------------- ws layout (float offsets) ----------------
#define OFF_CT     0                          // 4096 ushort = 2048 f  (Ct[m][e] bf16)
#define OFF_BM     2048                       // 64
#define OFF_WBAR   2112                       // 64
#define OFF_BBAR   2176                       // 1
#define OFF_RM0    2240                       // 64
#define OFF_P0     2304                       // 64
#define OFF_WSUM   2368                       // S*M = 12800 (zeroed by k_pre blocks 1..13)
#define OFF_EMSUM  (OFF_WSUM + S_LEN*M_SLOTS) // 200 (contiguous w/ wsum)
#define ZERO_CNT   (S_LEN*M_SLOTS + S_LEN)    // 13000 floats

// pack two f32 -> bf16 pair, round-to-nearest-even (for MFMA inputs)
__device__ __forceinline__ unsigned pk2rne(float lo, float hi) {
    unsigned ul = __float_as_uint(lo); ul += 0x7fffu + ((ul >> 16) & 1u);
    unsigned uh = __float_as_uint(hi); uh += 0x7fffu + ((uh >> 16) & 1u);
    return __builtin_amdgcn_perm(uh, ul, 0x07060302u);
}
__device__ __forceinline__ unsigned short bf16rne(float f) {
    unsigned u = __float_as_uint(f);
    return (unsigned short)((u + 0x7fffu + ((u >> 16) & 1u)) >> 16);
}
__device__ __forceinline__ short8 as_s8(uint4 u) { return __builtin_bit_cast(short8, u); }

__device__ __forceinline__ void gpcm_store(float th, int q,
                                           const float* __restrict__ alpha_mean,
                                           const float* __restrict__ beta_base,
                                           const float* __restrict__ beta_gaps,
                                           float* __restrict__ out, size_t idx) {
    float a  = __expf(alpha_mean[q]);
    float b0 = beta_base[q];
    float2 g = *reinterpret_cast<const float2*>(&beta_gaps[q * (K_CAT - 2)]);
    float g0 = log1pf(__expf(g.x));
    float g1 = log1pf(__expf(g.y));
    float be1 = b0 + g0;
    float be2 = be1 + g1;
    float z0 = a * (th - b0);
    float z1 = a * (th - be1);
    float z2 = a * (th - be2);
    float c1 = z0, c2 = z0 + z1, c3 = z0 + z1 + z2;
    float cm = fmaxf(fmaxf(0.f, c1), fmaxf(c2, c3));
    float e0 = __expf(0.f - cm), e1 = __expf(c1 - cm), e2 = __expf(c2 - cm), e3 = __expf(c3 - cm);
    float si = __fdividef(1.0f, e0 + e1 + e2 + e3);
    float4 o4 = make_float4(e0 * si, e1 * si, e2 * si, e3 * si);
    *reinterpret_cast<float4*>(&out[idx * K_CAT]) = o4;
}

// Gather the lane's q-row slices (issue early to hide latency).
__device__ __forceinline__ void load_qf(const float* __restrict__ qrow, int h, float4 qf[8]) {
    #pragma unroll
    for (int s = 0; s < 4; ++s) {
        const float4* src = (const float4*)(qrow + s * 16 + h * 8);
        qf[2 * s]     = src[0];
        qf[2 * s + 1] = src[1];
    }
}

// Load the lane's 8 Ct A-fragments once (t-invariant).
__device__ __forceinline__ void load_afrags(const unsigned short* __restrict__ ct,
                                            int h, int p, uint4 af[8]) {
    #pragma unroll
    for (int mt = 0; mt < 2; ++mt)
        #pragma unroll
        for (int s = 0; s < 4; ++s)
            af[mt * 4 + s] = *(const uint4*)(ct + (p + 32 * mt) * E_DIM + s * 16 + h * 8);
}

// 32x32x16 MFMA logits from preloaded qf + af: acc[mt][j] = logit for
// m = (j&3) + 8*((j>>2)&3) + 4*h + 32*mt, pair col p.
__device__ __forceinline__ void mfma_logits(
    const float4 qf[8], const uint4 af[8],
    const float* __restrict__ bm, int h, f32x16 acc[2])
{
    #pragma unroll
    for (int mt = 0; mt < 2; ++mt)
        #pragma unroll
        for (int g = 0; g < 4; ++g) {
            float4 v = *(const float4*)(bm + 8 * g + 4 * h + 32 * mt);
            acc[mt][4 * g + 0] = v.x; acc[mt][4 * g + 1] = v.y;
            acc[mt][4 * g + 2] = v.z; acc[mt][4 * g + 3] = v.w;
        }
    #pragma unroll
    for (int s = 0; s < 4; ++s) {
        uint4 bf;
        bf.x = pk2rne(qf[2 * s].x,     qf[2 * s].y);
        bf.y = pk2rne(qf[2 * s].z,     qf[2 * s].w);
        bf.z = pk2rne(qf[2 * s + 1].x, qf[2 * s + 1].y);
        bf.w = pk2rne(qf[2 * s + 1].z, qf[2 * s + 1].w);
        short8 bfr = as_s8(bf);
        acc[0] = __builtin_amdgcn_mfma_f32_32x32x16_bf16(as_s8(af[s]),     bfr, acc[0], 0, 0, 0);
        acc[1] = __builtin_amdgcn_mfma_f32_32x32x16_bf16(as_s8(af[4 + s]), bfr, acc[1], 0, 0, 0);
    }
}

// softmax (64 slots, this lane holds 32) + pair-fold; writes lane's folded
// value (sum over this wave's 32 pairs of attn[m]) into lsFoldRow[m].
__device__ __forceinline__ void softmax_fold(
    const f32x16 acc[2], int lane, int h, float* lsFoldRow)
{
    float av[32];
    float ssum = 0.f;
    #pragma unroll
    for (int j = 0; j < 16; ++j) { av[j]      = __expf(acc[0][j]); ssum += av[j]; }
    #pragma unroll
    for (int j = 0; j < 16; ++j) { av[16 + j] = __expf(acc[1][j]); ssum += av[16 + j]; }
    ssum += __shfl_xor(ssum, 32);
    const float inv = __fdividef(1.0f, ssum);
    #pragma unroll
    for (int j = 0; j < 32; ++j) av[j] *= inv;
    #pragma unroll
    for (int step = 0; step < 5; ++step) {
        const int sh = 1 << step;
        #pragma unroll
        for (int j = 0; j < (32 >> step) / 2; ++j) {
            float p0 = av[2 * j]     + __shfl_xor(av[2 * j], sh);
            float p1 = av[2 * j + 1] + __shfl_xor(av[2 * j + 1], sh);
            av[j] = (lane & sh) ? p1 : p0;
        }
    }
    const int jj = lane & 31;
    const int m = (jj & 3) + 8 * ((jj >> 2) & 3) + 4 * h + 32 * (jj >> 4);
    lsFoldRow[m] = av[0];
}

// k_pre: 14 blocks. Block 0: 4 waves, each one 32x32 Ct tile via MFMA + side
// duties. Blocks 1..13: zero wsum/emsum with float4 stores. (r14-verified)
__global__ __launch_bounds__(256) void k_pre(
    const float* __restrict__ q2k_w, const float* __restrict__ q2k_b,
    const float* __restrict__ mkeys,
    const float* __restrict__ ev_w, const float* __restrict__ ev_b,
    const float* __restrict__ means, const float* __restrict__ logvars,
    float* __restrict__ ws)
{
    const int tid = threadIdx.x;
    if (blockIdx.x != 0) {
        int i = ((int)blockIdx.x - 1) * 1024 + tid * 4;
        if (i + 4 <= ZERO_CNT) {
            *reinterpret_cast<float4*>(ws + OFF_WSUM + i) = make_float4(0.f, 0.f, 0.f, 0.f);
        } else {
            for (int j = i; j < ZERO_CNT; ++j) ws[OFF_WSUM + j] = 0.f;
        }
        return;
    }
    const int wv = tid >> 6, lane = tid & 63;
    const int h = lane >> 5, p = lane & 31;

    {
        const int m0 = (wv & 1) * 32, e0 = (wv >> 1) * 32;
        f32x16 d;
        #pragma unroll
        for (int i = 0; i < 16; ++i) d[i] = 0.f;
        #pragma unroll
        for (int s = 0; s < 4; ++s) {
            const float* ar = mkeys + (m0 + p) * KEY_DIM + s * 16 + h * 8;
            const float* br = q2k_w + (e0 + p) * KEY_DIM + s * 16 + h * 8;
            float4 a0 = *(const float4*)ar, a1 = *(const float4*)(ar + 4);
            float4 b0 = *(const float4*)br, b1 = *(const float4*)(br + 4);
            uint4 au, bu;
            au.x = pk2rne(a0.x, a0.y); au.y = pk2rne(a0.z, a0.w);
            au.z = pk2rne(a1.x, a1.y); au.w = pk2rne(a1.z, a1.w);
            bu.x = pk2rne(b0.x, b0.y); bu.y = pk2rne(b0.z, b0.w);
            bu.z = pk2rne(b1.x, b1.y); bu.w = pk2rne(b1.z, b1.w);
            d = __builtin_amdgcn_mfma_f32_32x32x16_bf16(as_s8(au), as_s8(bu), d, 0, 0, 0);
        }
        unsigned short* ct = (unsigned short*)ws;
        #pragma unroll
        for (int j = 0; j < 16; ++j) {
            int row = (j & 3) + 8 * ((j >> 2) & 3) + 4 * h;
            ct[(m0 + row) * E_DIM + e0 + p] = bf16rne(d[j]);
        }
    }

    if (wv == 0) {          // wbar[e]
        float s = 0.f;
        const float4* er = (const float4*)(ev_w + (size_t)lane * V_DIM);
        #pragma unroll
        for (int i = 0; i < V_DIM / 4; ++i) {
            float4 v = er[i];
            s += (v.x + v.y) + (v.z + v.w);
        }
        ws[OFF_WBAR + lane] = s * (1.0f / V_DIM);
    } else if (wv == 1) {   // bm, bbar
        float s = 0.f;
        const float4* mk = (const float4*)(mkeys + lane * KEY_DIM);
        const float4* qb = (const float4*)q2k_b;
        #pragma unroll
        for (int i = 0; i < KEY_DIM / 4; ++i) {
            float4 a = mk[i], c = qb[i];
            s += a.x * c.x + a.y * c.y + a.z * c.z + a.w * c.w;
        }
        ws[OFF_BM + lane] = s;
        float bbv = ev_b[lane] + ev_b[64 + lane];
        #pragma unroll
        for (int o = 32; o; o >>= 1) bbv += __shfl_xor(bbv, o);
        if (!lane) ws[OFF_BBAR] = bbv * (1.0f / V_DIM);
    } else if (wv == 2) {   // rm0/p0
        float s = 0.f;
        const float4* mr = (const float4*)(means + (size_t)lane * V_DIM);
        #pragma unroll
        for (int i = 0; i < V_DIM / 4; ++i) {
            float4 v = mr[i];
            s += (v.x + v.y) + (v.z + v.w);
        }
        ws[OFF_RM0 + lane] = s * (1.0f / V_DIM);
        ws[OFF_P0 + lane]  = __expf(-logvars[(size_t)lane * V_DIM]);  // row-uniform
    }
}

// Stats: 2 t's per block. A-frags hoisted; 4-wave LDS fold -> 128 atomics/block
// (was 512): 4x less device-scope atomic contention.
__global__ __launch_bounds__(256, 3) void k_attn(
    const float* __restrict__ qtab, const int* __restrict__ qs, const int* __restrict__ rs,
    const float* __restrict__ ws_ro,
    const float* __restrict__ qa_w, const float* __restrict__ qa_b,
    float* __restrict__ wsum, float* __restrict__ emsum,
    int B, float invNQ)
{
    __shared__ float4 lsEv[64];
    __shared__ float lsFold[2][4][M_SLOTS];
    const int tid = threadIdx.x, wv = tid >> 6, lane = tid & 63;
    const int h = lane >> 5, p = lane & 31;
    const int t0 = blockIdx.x * 2, t1 = t0 + 1;
    const int b = blockIdx.y * 128 + wv * 32 + p;

    const int q0 = qs[(size_t)b * S_LEN + t0];
    const int r0 = rs[(size_t)b * S_LEN + t0];
    const int q1 = qs[(size_t)b * S_LEN + t1];   // same line as t0
    const int r1 = rs[(size_t)b * S_LEN + t1];
    float4 qf0[8], qf1[8];
    load_qf(qtab + (size_t)q0 * E_DIM, h, qf0);  // both gathers in flight
    load_qf(qtab + (size_t)q1 * E_DIM, h, qf1);

    uint4 af[8];
    load_afrags((const unsigned short*)ws_ro, h, p, af);   // t-invariant

    if (tid < 64) lsEv[tid] = make_float4(qa_w[tid], qa_w[E_DIM + tid], qa_b[tid],
                                          ws_ro[OFF_WBAR + tid]);
    const float bb = ws_ro[OFF_BBAR];

    {
        f32x16 acc[2];
        mfma_logits(qf0, af, ws_ro + OFF_BM, h, acc);
        softmax_fold(acc, lane, h, &lsFold[0][wv][0]);
    }
    {
        f32x16 acc[2];
        mfma_logits(qf1, af, ws_ro + OFF_BM, h, acc);
        softmax_fold(acc, lane, h, &lsFold[1][wv][0]);
    }

    __syncthreads();   // lsEv + lsFold ready

    if (wv < 2) {      // wave 0 -> t0, wave 1 -> t1: one atomic per lane
        float s4 = (lsFold[wv][0][lane] + lsFold[wv][1][lane])
                 + (lsFold[wv][2][lane] + lsFold[wv][3][lane]);
        atomicAdd(&wsum[(wv ? t1 : t0) * M_SLOTS + lane], s4);
    }

    // evidence scalars for both t's
    float ev0 = 0.f, ev1 = 0.f;
    const float qn0 = (float)q0 * invNQ, rn0 = (float)r0 * (1.0f / (K_CAT - 1));
    const float qn1 = (float)q1 * invNQ, rn1 = (float)r1 * (1.0f / (K_CAT - 1));
    #pragma unroll 8
    for (int e = 0; e < 32; ++e) {
        float4 pv = lsEv[h * 32 + e];
        float qa0 = fmaf(qn0, pv.x, fmaf(rn0, pv.y, pv.z));
        float qa1 = fmaf(qn1, pv.x, fmaf(rn1, pv.y, pv.z));
        float ez0 = __expf(2.0f * qa0);
        float ez1 = __expf(2.0f * qa1);
        ev0 = fmaf(__fdividef(ez0 - 1.0f, ez0 + 1.0f), pv.w, ev0);
        ev1 = fmaf(__fdividef(ez1 - 1.0f, ez1 + 1.0f), pv.w, ev1);
    }
    ev0 += __shfl_xor(ev0, 32); ev0 += bb;
    ev1 += __shfl_xor(ev1, 32); ev1 += bb;
    #pragma unroll
    for (int o = 16; o; o >>= 1) { ev0 += __shfl_xor(ev0, o); ev1 += __shfl_xor(ev1, o); }
    if (!lane) {
        atomicAdd(&emsum[t0], ev0);
        atomicAdd(&emsum[t1], ev1);
    }
}

// Output: 2 t's per block. Prefix 4-way unrolled (4 independent accumulator
// pairs -> exposed L3 latency /4); t1's rm = t0's + one step. A-frags hoisted.
__global__ __launch_bounds__(256, 3) void k_out(
    const float* __restrict__ qtab, const int* __restrict__ qs,
    const float* __restrict__ ws_ro,
    const float* __restrict__ alpha_mean, const float* __restrict__ beta_base,
    const float* __restrict__ beta_gaps, float* __restrict__ out, int B, float invB)
{
    __shared__ float lsW[4][M_SLOTS], lsN[4][M_SLOTS];
    __shared__ float lsRmP0[M_SLOTS], lsRmP1[M_SLOTS];
    const int tid = threadIdx.x, wv = tid >> 6, lane = tid & 63;
    const int h = lane >> 5, p = lane & 31;
    const int t0 = blockIdx.x * 2, t1 = t0 + 1;
    const int b = blockIdx.y * 128 + wv * 32 + p;

    const int q0 = qs[(size_t)b * S_LEN + t0];
    const int q1 = qs[(size_t)b * S_LEN + t1];
    float4 qf0[8], qf1[8];
    load_qf(qtab + (size_t)q0 * E_DIM, h, qf0);  // issue gathers BEFORE prefix
    load_qf(qtab + (size_t)q1 * E_DIM, h, qf1);

    uint4 af[8];
    load_afrags((const unsigned short*)ws_ro, h, p, af);   // t-invariant

    // prefix partials over [0, t0): wave wv sums its segment, 4-way unrolled
    {
        const float* wsum  = ws_ro + OFF_WSUM;
        const float* emsum = ws_ro + OFF_EMSUM;
        const int seg = (t0 + 3) >> 2;
        const int s0 = wv * seg, s1 = min(s0 + seg, t0);
        float pw0 = 0.f, pn0 = 0.f, pw1 = 0.f, pn1 = 0.f;
        float pw2 = 0.f, pn2 = 0.f, pw3 = 0.f, pn3 = 0.f;
        int s = s0;
        for (; s + 4 <= s1; s += 4) {
            float w0 = wsum[(s + 0) * M_SLOTS + lane];
            float w1 = wsum[(s + 1) * M_SLOTS + lane];
            float w2 = wsum[(s + 2) * M_SLOTS + lane];
            float w3 = wsum[(s + 3) * M_SLOTS + lane];
            float e0 = emsum[s + 0], e1 = emsum[s + 1];
            float e2 = emsum[s + 2], e3 = emsum[s + 3];
            pw0 += w0; pn0 = fmaf(e0, w0, pn0);
            pw1 += w1; pn1 = fmaf(e1, w1, pn1);
            pw2 += w2; pn2 = fmaf(e2, w2, pn2);
            pw3 += w3; pn3 = fmaf(e3, w3, pn3);
        }
        for (; s < s1; ++s) {
            float w = wsum[s * M_SLOTS + lane];
            pw0 += w; pn0 = fmaf(emsum[s], w, pn0);
        }
        lsW[wv][lane] = (pw0 + pw1) + (pw2 + pw3);
        lsN[wv][lane] = (pn0 + pn1) + (pn2 + pn3);
    }
    __syncthreads();
    if (tid < 64) {
        const int m = tid;
        float sw = lsW[0][m] + lsW[1][m] + lsW[2][m] + lsW[3][m];
        float sn = lsN[0][m] + lsN[1][m] + lsN[2][m] + lsN[3][m];
        const float p0v = ws_ro[OFF_P0 + m];
        float den0 = p0v + sw * invB;
        float num0 = fmaf(p0v, ws_ro[OFF_RM0 + m], sn * (invB * invB));
        // one more step for t1: include stats of step t0
        float wstep = ws_ro[OFF_WSUM + t0 * M_SLOTS + m];
        float estep = ws_ro[OFF_EMSUM + t0];
        float den1 = den0 + wstep * invB;
        float num1 = fmaf(estep * wstep, invB * invB, num0);
        // MFMA slot-permuted index: idx = h(m)*32 + mt(m)*16 + j(m)
        const int idx = ((m >> 2) & 1) * 32 + ((m >> 5) & 1) * 16 + (m & 3) + 4 * ((m >> 3) & 3);
        lsRmP0[idx] = num0 / den0;
        lsRmP1[idx] = num1 / den1;
    }
    __syncthreads();

    #pragma unroll
    for (int it = 0; it < 2; ++it) {
        f32x16 acc[2];
        mfma_logits(it ? qf1 : qf0, af, ws_ro + OFF_BM, h, acc);
        const float* rmh = (it ? lsRmP1 : lsRmP0) + h * 32;
        float ssum = 0.f, th = 0.f;
        #pragma unroll
        for (int j = 0; j < 16; ++j) {
            float e = __expf(acc[0][j]);
            ssum += e;
            th = fmaf(e, rmh[j], th);
        }
        #pragma unroll
        for (int j = 0; j < 16; ++j) {
            float e = __expf(acc[1][j]);
            ssum += e;
            th = fmaf(e, rmh[16 + j], th);
        }
        ssum += __shfl_xor(ssum, 32);
        th   += __shfl_xor(th, 32);
        th = __fdividef(th, ssum);
        if (!h) {
            const int t = it ? t1 : t0;
            const int q = it ? q1 : q0;
            gpcm_store(th, q, alpha_mean, beta_base, beta_gaps, out, (size_t)b * S_LEN + t);
        }
    }
}

extern "C" void kernel_launch(void* const* d_in, const int* in_sizes, int n_in,
                              void* d_out, int out_size, void* d_ws, size_t ws_size,
                              hipStream_t stream) {
    const float* qtab       = (const float*)d_in[0];
    const float* alpha_mean = (const float*)d_in[1];
    const float* beta_base  = (const float*)d_in[2];
    const float* beta_gaps  = (const float*)d_in[3];
    const float* ab_means   = (const float*)d_in[4];
    const float* ab_logvars = (const float*)d_in[5];
    const float* mkeys      = (const float*)d_in[6];
    const float* q2k_w      = (const float*)d_in[7];
    const float* q2k_b      = (const float*)d_in[8];
    const float* qa_w       = (const float*)d_in[9];
    const float* qa_b       = (const float*)d_in[10];
    const float* ev_w       = (const float*)d_in[11];
    const float* ev_b       = (const float*)d_in[12];
    const int*   qs         = (const int*)d_in[13];
    const int*   rs         = (const int*)d_in[14];
    float* out = (float*)d_out;
    float* ws  = (float*)d_ws;

    const int NQ = in_sizes[1];
    const int S  = S_LEN;
    const int B  = in_sizes[13] / S;   // 512

    float* wsum  = ws + OFF_WSUM;
    float* emsum = ws + OFF_EMSUM;

    k_pre<<<14, 256, 0, stream>>>(q2k_w, q2k_b, mkeys, ev_w, ev_b,
                                  ab_means, ab_logvars, ws);

    dim3 g(S / 2, B / 128);
    k_attn<<<g, 256, 0, stream>>>(qtab, qs, rs, ws, qa_w, qa_b,
                                  wsum, emsum, B, 1.0f / (float)NQ);

    k_out<<<g, 256, 0, stream>>>(qtab, qs, ws, alpha_mean, beta_base,
                                 beta_gaps, out, B, 1.0f / (float)B);
}